// Round 2
// baseline (492.955 us; speedup 1.0000x reference)
//
#include <hip/hip_runtime.h>

#define V_N 30000
#define E_N 500000
#define H_N 4
#define F_N 32
#define NEG 0.2f

__device__ __forceinline__ float lrelu(float x) { return x > 0.f ? x : NEG * x; }

// ---------------------------------------------------------------------------
// Kernel A: node transforms — 4 matrices fused.
// 32 lanes per row; weights in LDS; input row broadcast via shfl.
// ---------------------------------------------------------------------------
__global__ __launch_bounds__(256) void node_xform(
    const float* __restrict__ nf,
    const float* __restrict__ Was, const float* __restrict__ bas,
    const float* __restrict__ Wad, const float* __restrict__ bad,
    const float* __restrict__ Wms, const float* __restrict__ bms,
    const float* __restrict__ Wmd, const float* __restrict__ bmd,
    float* __restrict__ src_t, float* __restrict__ dst_t,
    float* __restrict__ msg_s, float* __restrict__ msg_d)
{
    __shared__ float w0[1024], w1[1024], w2[1024], w3[1024];
    int tid = threadIdx.x;
    for (int i = tid; i < 1024; i += 256) {
        w0[i] = Was[i]; w1[i] = Wad[i];
        w2[i] = Wms[i]; w3[i] = Wmd[i];
    }
    __syncthreads();
    int lane = tid & 31;
    int r = blockIdx.x * 8 + (tid >> 5);
    if (r >= V_N * H_N) return;           // exact division: never taken
    float x = nf[r * 32 + lane];
    float a0 = bas[lane], a1 = bad[lane];
    float a2 = bms[lane], a3 = bmd[lane];
    #pragma unroll
    for (int k = 0; k < 32; ++k) {
        float xk = __shfl(x, k, 32);
        a0 += xk * w0[k * 32 + lane];
        a1 += xk * w1[k * 32 + lane];
        a2 += xk * w2[k * 32 + lane];
        a3 += xk * w3[k * 32 + lane];
    }
    src_t[r * 32 + lane] = a0;
    dst_t[r * 32 + lane] = a1;
    msg_s[r * 32 + lane] = a2;
    msg_d[r * 32 + lane] = a3;
}

// ---------------------------------------------------------------------------
// Kernel B: per-edge attention scores + exp + segment-sum (no max shift:
// exp(s)/sum exp(s) is mathematically identical and |s| <~ 10).
// ---------------------------------------------------------------------------
__global__ __launch_bounds__(256) void edge_score(
    const float* __restrict__ ef, const int* __restrict__ src, const int* __restrict__ dst,
    const float* __restrict__ Wae, const float* __restrict__ bae,
    const float* __restrict__ Wdot, const float* __restrict__ bdot,
    const float* __restrict__ src_t, const float* __restrict__ dst_t,
    float* __restrict__ ex, float* __restrict__ ssum)
{
    __shared__ float wa[1024];
    __shared__ float wd[32];
    int tid = threadIdx.x;
    for (int i = tid; i < 1024; i += 256) wa[i] = Wae[i];
    if (tid < 32) wd[tid] = Wdot[tid];
    __syncthreads();
    int lane = tid & 31;
    int e = blockIdx.x * 8 + (tid >> 5);
    if (e >= E_N) return;                 // exact division: never taken
    float x = ef[e * 32 + lane];
    float ea = bae[lane];
    #pragma unroll
    for (int k = 0; k < 32; ++k) ea += __shfl(x, k, 32) * wa[k * 32 + lane];
    int si = src[e], di = dst[e];
    float bd = bdot[0];
    const float* sp = src_t + (size_t)si * H_N * 32;
    const float* dp = dst_t + (size_t)di * H_N * 32;
    #pragma unroll
    for (int h = 0; h < H_N; ++h) {
        float t = lrelu(sp[h * 32 + lane] + dp[h * 32 + lane] + ea) * wd[lane];
        #pragma unroll
        for (int off = 16; off; off >>= 1) t += __shfl_xor(t, off, 32);
        if (lane == 0) {
            float exv = __expf(t + bd);
            ex[e * H_N + h] = exv;
            atomicAdd(&ssum[(size_t)di * H_N + h], exv);
        }
    }
}

// ---------------------------------------------------------------------------
// Kernel C: per-edge message, alpha-weighted scatter-add into feat.
// ---------------------------------------------------------------------------
__global__ __launch_bounds__(256) void edge_msg(
    const float* __restrict__ ef, const int* __restrict__ src, const int* __restrict__ dst,
    const float* __restrict__ Wme, const float* __restrict__ bme,
    const float* __restrict__ msg_s, const float* __restrict__ msg_d,
    const float* __restrict__ ex, const float* __restrict__ ssum,
    float* __restrict__ feat)
{
    __shared__ float wm[1024];
    int tid = threadIdx.x;
    for (int i = tid; i < 1024; i += 256) wm[i] = Wme[i];
    __syncthreads();
    int lane = tid & 31;
    int e = blockIdx.x * 8 + (tid >> 5);
    if (e >= E_N) return;                 // exact division: never taken
    float x = ef[e * 32 + lane];
    float me = bme[lane];
    #pragma unroll
    for (int k = 0; k < 32; ++k) me += __shfl(x, k, 32) * wm[k * 32 + lane];
    int si = src[e], di = dst[e];
    const float* sp = msg_s + (size_t)si * H_N * 32;
    const float* dp = msg_d + (size_t)di * H_N * 32;
    #pragma unroll
    for (int h = 0; h < H_N; ++h) {
        float alpha = ex[e * H_N + h] / ssum[(size_t)di * H_N + h];
        float v = lrelu(sp[h * 32 + lane] + dp[h * 32 + lane] + me) * alpha;
        atomicAdd(&feat[((size_t)di * H_N + h) * 32 + lane], v);
    }
}

// ---------------------------------------------------------------------------
// Kernel D: out = lrelu(feat + nf @ W_wn + b_wn), f32 out.
// ---------------------------------------------------------------------------
__global__ __launch_bounds__(256) void finalize_k(
    const float* __restrict__ nf, const float* __restrict__ Wwn, const float* __restrict__ bwn,
    const float* __restrict__ feat, float* __restrict__ out)
{
    __shared__ float w[1024];
    int tid = threadIdx.x;
    for (int i = tid; i < 1024; i += 256) w[i] = Wwn[i];
    __syncthreads();
    int lane = tid & 31;
    int r = blockIdx.x * 8 + (tid >> 5);
    if (r >= V_N * H_N) return;           // exact division: never taken
    float x = nf[r * 32 + lane];
    float a = bwn[lane];
    #pragma unroll
    for (int k = 0; k < 32; ++k) a += __shfl(x, k, 32) * w[k * 32 + lane];
    out[r * 32 + lane] = lrelu(feat[r * 32 + lane] + a);
}

extern "C" void kernel_launch(void* const* d_in, const int* in_sizes, int n_in,
                              void* d_out, int out_size, void* d_ws, size_t ws_size,
                              hipStream_t stream)
{
    const float* nf  = (const float*)d_in[0];
    const float* ef  = (const float*)d_in[1];
    const int*   src = (const int*)d_in[2];
    const int*   dst = (const int*)d_in[3];
    const float* Was = (const float*)d_in[4],  *bas = (const float*)d_in[5];
    const float* Wad = (const float*)d_in[6],  *bad = (const float*)d_in[7];
    const float* Wae = (const float*)d_in[8],  *bae = (const float*)d_in[9];
    const float* Wdot= (const float*)d_in[10], *bdot= (const float*)d_in[11];
    const float* Wms = (const float*)d_in[12], *bms = (const float*)d_in[13];
    const float* Wmd = (const float*)d_in[14], *bmd = (const float*)d_in[15];
    const float* Wme = (const float*)d_in[16], *bme = (const float*)d_in[17];
    const float* Wwn = (const float*)d_in[18], *bwn = (const float*)d_in[19];

    float* ws = (float*)d_ws;
    const size_t nrow = (size_t)V_N * H_N;          // 120000
    float* src_t = ws;                              // nrow*32
    float* dst_t = src_t + nrow * 32;
    float* msg_s = dst_t + nrow * 32;
    float* msg_d = msg_s + nrow * 32;
    float* ex    = msg_d + nrow * 32;               // E*H
    float* ssum  = ex + (size_t)E_N * H_N;          // nrow   (zeroed)
    float* feat  = ssum + nrow;                     // nrow*32 (zeroed)

    // ssum and feat are adjacent: one async zero-fill (graph-capture safe).
    hipMemsetAsync(ssum, 0, (nrow + nrow * 32) * sizeof(float), stream);

    const int rb = (int)((nrow + 7) / 8);           // 15000 blocks
    const int eb = (E_N + 7) / 8;                   // 62500 blocks

    node_xform<<<rb, 256, 0, stream>>>(nf, Was, bas, Wad, bad, Wms, bms, Wmd, bmd,
                                       src_t, dst_t, msg_s, msg_d);
    edge_score<<<eb, 256, 0, stream>>>(ef, src, dst, Wae, bae, Wdot, bdot,
                                       src_t, dst_t, ex, ssum);
    edge_msg<<<eb, 256, 0, stream>>>(ef, src, dst, Wme, bme,
                                     msg_s, msg_d, ex, ssum, feat);
    finalize_k<<<rb, 256, 0, stream>>>(nf, Wwn, bwn, feat, (float*)d_out);
}